// Round 1
// baseline (684.275 us; speedup 1.0000x reference)
//
#include <hip/hip_runtime.h>
#include <math.h>

#define S_SEQ 256
#define T_TOK 512
#define BERT 768
#define POSD 128
#define H1 1024
#define NC 6

#define HALF_T 256     // tokens per block (2 blocks per sequence)
#define TILE_T 16      // tokens per LDS tile
#define NTILES (HALF_T / TILE_T)   // 16

// ---------------------------------------------------------------------------
// Kernel 1: fused attention-logit + online-softmax weighted pooling.
// grid = 512 (2 blocks per s), block = 256.
// Each block handles 256 tokens of one sequence, produces partial
// (m, l, acc[768]) for flash-style combination later.
// ---------------------------------------------------------------------------
__global__ __launch_bounds__(256, 2) void pool_kernel(
    const float* __restrict__ emb, const float* __restrict__ pos,
    const float* __restrict__ Wa, const float* __restrict__ ba,
    float* __restrict__ part_acc, float* __restrict__ part_ml)
{
    __shared__ float lds_tile[TILE_T * BERT];   // 48 KB
    __shared__ float lds_plog[HALF_T];          // 1 KB   pos-part of logits
    __shared__ float lds_logit[TILE_T];

    const int tid  = threadIdx.x;
    const int wave = tid >> 6;
    const int lane = tid & 63;
    const int b    = blockIdx.x;
    const int s    = b >> 1;
    const int t0   = (b & 1) * HALF_T;

    // --- register-held attention weights ---
    const float4* Wa4 = (const float4*)Wa;
    float4 wa_e[3];
    wa_e[0] = Wa4[lane];          // floats [lane*4 .. lane*4+3]
    wa_e[1] = Wa4[64 + lane];     // +256
    wa_e[2] = Wa4[128 + lane];    // +512
    const int lane32 = lane & 31;
    const int half32 = lane >> 5;
    const float4 wp = Wa4[192 + lane32];   // pos weights: floats [768 + lane32*4 ..]
    const float bav = ba[0];

    // --- phase 0: pos-part of logits. Each 32-lane half-wave does one token.
    const float4* pos4 = (const float4*)pos;
    #pragma unroll 4
    for (int it = 0; it < 32; ++it) {
        const int tl = wave * 64 + it * 2 + half32;        // 0..255
        const size_t gi = ((size_t)s * T_TOK + (t0 + tl)) * (POSD/4) + lane32;
        const float4 p = pos4[gi];
        float d = p.x*wp.x + p.y*wp.y + p.z*wp.z + p.w*wp.w;
        #pragma unroll
        for (int off = 16; off >= 1; off >>= 1) d += __shfl_xor(d, off, 32);
        if (lane32 == 0) lds_plog[tl] = d + bav;
    }

    // --- online softmax state ---
    float m = -INFINITY;
    float l = 0.f;
    float acc0 = 0.f, acc1 = 0.f, acc2 = 0.f;

    const float4* emb_blk4 =
        (const float4*)(emb + ((size_t)s * T_TOK + t0) * BERT);
    float4* lds4 = (float4*)lds_tile;

    for (int tt = 0; tt < NTILES; ++tt) {
        __syncthreads();   // previous tile fully consumed (and phase-0 done)

        // (a) stage 16x768 tile: 3072 float4 / 256 threads = 12 each
        {
            const float4* src = emb_blk4 + (size_t)tt * (TILE_T*BERT/4);
            float4 tmp[12];
            #pragma unroll
            for (int i = 0; i < 12; ++i) tmp[i] = src[i*256 + tid];
            #pragma unroll
            for (int i = 0; i < 12; ++i) lds4[i*256 + tid] = tmp[i];
        }
        __syncthreads();   // tile visible

        // (c) logits: 4 tokens per wave, full-wave reduced dot over 768
        #pragma unroll
        for (int q = 0; q < 4; ++q) {
            const int t = wave * 4 + q;
            const float4* row4 = (const float4*)&lds_tile[t * BERT];
            float d = 0.f;
            #pragma unroll
            for (int i = 0; i < 3; ++i) {
                const float4 v = row4[i*64 + lane];
                d += v.x*wa_e[i].x + v.y*wa_e[i].y + v.z*wa_e[i].z + v.w*wa_e[i].w;
            }
            #pragma unroll
            for (int off = 32; off >= 1; off >>= 1) d += __shfl_xor(d, off, 64);
            if (lane == 0) lds_logit[t] = d + lds_plog[tt*TILE_T + t];
        }
        __syncthreads();   // logits visible

        // (e) online softmax update (redundant scalar part per thread)
        float tmax = lds_logit[0];
        #pragma unroll
        for (int t = 1; t < TILE_T; ++t) tmax = fmaxf(tmax, lds_logit[t]);
        const float m_new = fmaxf(m, tmax);
        const float alpha = __expf(m - m_new);   // first tile: exp(-inf)=0
        float p[TILE_T];
        float psum = 0.f;
        #pragma unroll
        for (int t = 0; t < TILE_T; ++t) {
            p[t] = __expf(lds_logit[t] - m_new);
            psum += p[t];
        }
        l = l * alpha + psum;
        acc0 *= alpha; acc1 *= alpha; acc2 *= alpha;
        #pragma unroll
        for (int t = 0; t < TILE_T; ++t) {
            acc0 = fmaf(p[t], lds_tile[t*BERT +       tid], acc0);
            acc1 = fmaf(p[t], lds_tile[t*BERT + 256 + tid], acc1);
            acc2 = fmaf(p[t], lds_tile[t*BERT + 512 + tid], acc2);
        }
        m = m_new;
    }

    part_acc[(size_t)b*BERT +       tid] = acc0;
    part_acc[(size_t)b*BERT + 256 + tid] = acc1;
    part_acc[(size_t)b*BERT + 512 + tid] = acc2;
    if (tid == 0) { part_ml[b*2] = m; part_ml[b*2+1] = l; }
}

// ---------------------------------------------------------------------------
// Kernel 2: combine the two halves per sequence (softmax partial merge),
// normalize, and segment-sum into vecs[64][768]. grid = 64, block = 256.
// ---------------------------------------------------------------------------
__global__ void combine_segsum(
    const float* __restrict__ part_acc, const float* __restrict__ part_ml,
    const int* __restrict__ seg, float* __restrict__ vecs)
{
    const int c = blockIdx.x;
    const int tid = threadIdx.x;
    float v0 = 0.f, v1 = 0.f, v2 = 0.f;
    for (int s = 0; s < S_SEQ; ++s) {
        if (seg[s] != c) continue;
        const int p0 = 2*s, p1 = 2*s + 1;
        const float m0 = part_ml[p0*2], l0 = part_ml[p0*2+1];
        const float m1 = part_ml[p1*2], l1 = part_ml[p1*2+1];
        const float M  = fmaxf(m0, m1);
        const float e0 = __expf(m0 - M), e1 = __expf(m1 - M);
        const float inv = 1.0f / (l0*e0 + l1*e1);
        const float a = e0 * inv, bb = e1 * inv;
        v0 += a*part_acc[(size_t)p0*BERT +       tid] + bb*part_acc[(size_t)p1*BERT +       tid];
        v1 += a*part_acc[(size_t)p0*BERT + 256 + tid] + bb*part_acc[(size_t)p1*BERT + 256 + tid];
        v2 += a*part_acc[(size_t)p0*BERT + 512 + tid] + bb*part_acc[(size_t)p1*BERT + 512 + tid];
    }
    vecs[(size_t)c*BERT +       tid] = v0;
    vecs[(size_t)c*BERT + 256 + tid] = v1;
    vecs[(size_t)c*BERT + 512 + tid] = v2;
}

// ---------------------------------------------------------------------------
// Kernel 3/4: dense layer out = leaky_relu(in @ W + b), W is [K][1024].
// grid = dim3(4, 64) (j-tile, comment), block = 256.
// ---------------------------------------------------------------------------
__global__ void mlp_layer(
    const float* __restrict__ in, const float* __restrict__ W,
    const float* __restrict__ bias, float* __restrict__ out, int K)
{
    __shared__ float v[H1];   // input row (K <= 1024)
    const int c  = blockIdx.y;
    const int tid = threadIdx.x;
    const int j  = blockIdx.x * 256 + tid;
    for (int i = tid; i < K; i += 256) v[i] = in[(size_t)c*K + i];
    __syncthreads();
    float a0 = 0.f, a1 = 0.f, a2 = 0.f, a3 = 0.f;
    #pragma unroll 4
    for (int k = 0; k < K; k += 4) {
        a0 = fmaf(v[k  ], W[(size_t)(k  )*H1 + j], a0);
        a1 = fmaf(v[k+1], W[(size_t)(k+1)*H1 + j], a1);
        a2 = fmaf(v[k+2], W[(size_t)(k+2)*H1 + j], a2);
        a3 = fmaf(v[k+3], W[(size_t)(k+3)*H1 + j], a3);
    }
    const float acc = bias[j] + ((a0 + a1) + (a2 + a3));
    out[(size_t)c*H1 + j] = acc > 0.f ? acc : 0.01f * acc;
}

// ---------------------------------------------------------------------------
// Kernel 5: out = sigmoid(h @ W3 + b3). grid = 64, block = 256.
// ---------------------------------------------------------------------------
__global__ void mlp_out(
    const float* __restrict__ h, const float* __restrict__ W3,
    const float* __restrict__ b3, float* __restrict__ out)
{
    __shared__ float v[H1];
    __shared__ float red[NC][4];
    const int c = blockIdx.x;
    const int tid = threadIdx.x;
    const int wave = tid >> 6, lane = tid & 63;
    for (int i = tid; i < H1; i += 256) v[i] = h[(size_t)c*H1 + i];
    __syncthreads();
    float po[NC] = {0.f, 0.f, 0.f, 0.f, 0.f, 0.f};
    for (int k = tid; k < H1; k += 256) {
        const float hv = v[k];
        #pragma unroll
        for (int o = 0; o < NC; ++o) po[o] = fmaf(hv, W3[k*NC + o], po[o]);
    }
    #pragma unroll
    for (int o = 0; o < NC; ++o) {
        float d = po[o];
        #pragma unroll
        for (int off = 32; off >= 1; off >>= 1) d += __shfl_xor(d, off, 64);
        if (lane == 0) red[o][wave] = d;
    }
    __syncthreads();
    if (tid < NC) {
        const float sum = red[tid][0] + red[tid][1] + red[tid][2] + red[tid][3] + b3[tid];
        out[c*NC + tid] = 1.0f / (1.0f + __expf(-sum));
    }
}

// ---------------------------------------------------------------------------
extern "C" void kernel_launch(void* const* d_in, const int* in_sizes, int n_in,
                              void* d_out, int out_size, void* d_ws, size_t ws_size,
                              hipStream_t stream)
{
    const float* emb = (const float*)d_in[0];
    const float* pos = (const float*)d_in[1];
    const float* Wa  = (const float*)d_in[2];
    const float* ba  = (const float*)d_in[3];
    const float* W1  = (const float*)d_in[4];
    const float* b1  = (const float*)d_in[5];
    const float* W2  = (const float*)d_in[6];
    const float* b2  = (const float*)d_in[7];
    const float* W3  = (const float*)d_in[8];
    const float* b3  = (const float*)d_in[9];
    const int*   seg = (const int*)d_in[10];
    float* out = (float*)d_out;

    float* ws = (float*)d_ws;
    float* part_acc = ws;                       // 512*768
    float* part_ml  = part_acc + 512*BERT;      // 512*2
    float* vecs     = part_ml  + 512*2;         // 64*768
    float* h1       = vecs     + 64*BERT;       // 64*1024
    float* h2       = h1       + 64*H1;         // 64*1024

    pool_kernel<<<512, 256, 0, stream>>>(emb, pos, Wa, ba, part_acc, part_ml);
    combine_segsum<<<64, 256, 0, stream>>>(part_acc, part_ml, seg, vecs);
    mlp_layer<<<dim3(4, 64), 256, 0, stream>>>(vecs, W1, b1, h1, BERT);
    mlp_layer<<<dim3(4, 64), 256, 0, stream>>>(h1, W2, b2, h2, H1);
    mlp_out<<<64, 256, 0, stream>>>(h2, W3, b3, out);
}